// Round 6
// baseline (429.830 us; speedup 1.0000x reference)
//
#include <hip/hip_runtime.h>
#include <math.h>

#define N_NODES 8192
#define E_EDGES 262144
#define ETOT (E_EDGES + N_NODES)
#define F_IN 256
#define NH 4
#define NC 32
#define DD 128
#define NEG_SLOPE 0.2f
#define LN_EPS 1e-5f
// attention softmax in exp2 domain: fold log2(e)/sqrt(32) into Q at pack time
#define QK_SCALE (1.4426950408889634f / 5.656854249492381f)

typedef __attribute__((ext_vector_type(8))) short bf16x8;
typedef __attribute__((ext_vector_type(4))) float f32x4;

__device__ __forceinline__ float fexp2(float x) { return __builtin_amdgcn_exp2f(x); }
__device__ __forceinline__ float flog2(float x) { return __builtin_amdgcn_logf(x); }
__device__ __forceinline__ float frcp(float x)  { return __builtin_amdgcn_rcpf(x); }

__device__ __forceinline__ unsigned short f2bf(float f) {   // RTNE
    unsigned u = __float_as_uint(f);
    u += 0x7FFFu + ((u >> 16) & 1u);
    return (unsigned short)(u >> 16);
}
// pack two floats -> two bf16 (round-half-up) in one v_perm
__device__ __forceinline__ unsigned pk2bf(float lo, float hi) {
    unsigned a = __float_as_uint(lo) + 0x8000u;
    unsigned b = __float_as_uint(hi) + 0x8000u;
    return __builtin_amdgcn_perm(b, a, 0x07060302u);
}

// ===== GEMM xw = x @ Wgat (K=256), fused attention-coefficient epilogue =====
// A row addresses are block-uniform -> no LDS staging, scalar-cache loads.
__global__ __launch_bounds__(128) void k_gemm_att(const float* __restrict__ A,
                                                  const float* __restrict__ W,
                                                  float* __restrict__ out,
                                                  const float* __restrict__ att_src,
                                                  const float* __restrict__ att_dst,
                                                  float* __restrict__ asrc,
                                                  float* __restrict__ adst) {
    const int tid = threadIdx.x;
    const int r0 = blockIdx.x * 16;
    float acc[16];
#pragma unroll
    for (int r = 0; r < 16; ++r) acc[r] = 0.f;
    for (int k = 0; k < F_IN; k += 4) {
        float w0 = W[(size_t)k * 128 + tid];
        float w1 = W[(size_t)(k + 1) * 128 + tid];
        float w2 = W[(size_t)(k + 2) * 128 + tid];
        float w3 = W[(size_t)(k + 3) * 128 + tid];
#pragma unroll
        for (int r = 0; r < 16; ++r) {
            float4 av = *(const float4*)&A[(size_t)(r0 + r) * F_IN + k];
            acc[r] += av.x * w0 + av.y * w1 + av.z * w2 + av.w * w3;
        }
    }
#pragma unroll
    for (int r = 0; r < 16; ++r) out[(size_t)(r0 + r) * 128 + tid] = acc[r];
    float avs = att_src[tid], avd = att_dst[tid];
    int h = tid >> 5;
#pragma unroll
    for (int r = 0; r < 16; ++r) {
        float vs = acc[r] * avs, vd = acc[r] * avd;
#pragma unroll
        for (int off = 1; off < 32; off <<= 1) {
            vs += __shfl_xor(vs, off);
            vd += __shfl_xor(vd, off);
        }
        if ((tid & 31) == 0) {
            asrc[(r0 + r) * 4 + h] = vs;
            adst[(r0 + r) * 4 + h] = vd;
        }
    }
}

// ===== GEMM hbuf = hcat @ Wpro (K=128) + transposed bf16 Htb[128][8192] =====
__global__ __launch_bounds__(128) void k_gemm_pro(const float* __restrict__ A,
                                                  const float* __restrict__ W,
                                                  float* __restrict__ out,
                                                  unsigned short* __restrict__ Htb) {
    const int tid = threadIdx.x;
    const int r0 = blockIdx.x * 16;
    float acc[16];
#pragma unroll
    for (int r = 0; r < 16; ++r) acc[r] = 0.f;
    for (int k = 0; k < DD; k += 4) {
        float w0 = W[(size_t)k * 128 + tid];
        float w1 = W[(size_t)(k + 1) * 128 + tid];
        float w2 = W[(size_t)(k + 2) * 128 + tid];
        float w3 = W[(size_t)(k + 3) * 128 + tid];
#pragma unroll
        for (int r = 0; r < 16; ++r) {
            float4 av = *(const float4*)&A[(size_t)(r0 + r) * DD + k];
            acc[r] += av.x * w0 + av.y * w1 + av.z * w2 + av.w * w3;
        }
    }
#pragma unroll
    for (int r = 0; r < 16; ++r) out[(size_t)(r0 + r) * 128 + tid] = acc[r];
    uint4 p0, p1;
    p0.x = (unsigned)f2bf(acc[0]) | ((unsigned)f2bf(acc[1]) << 16);
    p0.y = (unsigned)f2bf(acc[2]) | ((unsigned)f2bf(acc[3]) << 16);
    p0.z = (unsigned)f2bf(acc[4]) | ((unsigned)f2bf(acc[5]) << 16);
    p0.w = (unsigned)f2bf(acc[6]) | ((unsigned)f2bf(acc[7]) << 16);
    p1.x = (unsigned)f2bf(acc[8]) | ((unsigned)f2bf(acc[9]) << 16);
    p1.y = (unsigned)f2bf(acc[10]) | ((unsigned)f2bf(acc[11]) << 16);
    p1.z = (unsigned)f2bf(acc[12]) | ((unsigned)f2bf(acc[13]) << 16);
    p1.w = (unsigned)f2bf(acc[14]) | ((unsigned)f2bf(acc[15]) << 16);
    *(uint4*)(Htb + (size_t)tid * N_NODES + r0) = p0;
    *(uint4*)(Htb + (size_t)tid * N_NODES + r0 + 8) = p1;
}

__device__ __forceinline__ void edge_sd(int e, const int* adj, int& s, int& d) {
    if (e < E_EDGES) { s = adj[e]; d = adj[E_EDGES + e]; }
    else { s = e - E_EDGES; d = s; }
}

// ===== edge pass: degree count + exp(leaky) + denom sum (no max: shift-invariant) =====
__global__ void k_edge_pass1(const int* __restrict__ adj, const float* __restrict__ asrc,
                             const float* __restrict__ adst, float* __restrict__ elbuf,
                             float* __restrict__ nodesum, int* __restrict__ deg) {
    int e = blockIdx.x * blockDim.x + threadIdx.x;
    if (e >= ETOT) return;
    int s, d; edge_sd(e, adj, s, d);
    atomicAdd(&deg[d], 1);
    float4 as4 = *(const float4*)&asrc[s * 4];
    float4 ad4 = *(const float4*)&adst[d * 4];
    const float L2E = 1.4426950408889634f;
    float4 p;
    float v;
    v = as4.x + ad4.x; v = v > 0.f ? v : NEG_SLOPE * v; p.x = fexp2(v * L2E);
    v = as4.y + ad4.y; v = v > 0.f ? v : NEG_SLOPE * v; p.y = fexp2(v * L2E);
    v = as4.z + ad4.z; v = v > 0.f ? v : NEG_SLOPE * v; p.z = fexp2(v * L2E);
    v = as4.w + ad4.w; v = v > 0.f ? v : NEG_SLOPE * v; p.w = fexp2(v * L2E);
    *(float4*)&elbuf[(size_t)e * 4] = p;
    atomicAdd(&nodesum[d * 4 + 0], p.x);
    atomicAdd(&nodesum[d * 4 + 1], p.y);
    atomicAdd(&nodesum[d * 4 + 2], p.z);
    atomicAdd(&nodesum[d * 4 + 3], p.w);
}

// ===== single-block exclusive scan over deg[8192] -> rowptr, cursor =====
__global__ __launch_bounds__(1024) void k_scan(const int* __restrict__ deg,
                                               int* __restrict__ rowptr,
                                               int* __restrict__ cursor) {
    __shared__ int sm[1024];
    int t = threadIdx.x;
    int v[8], sum = 0;
#pragma unroll
    for (int j = 0; j < 8; ++j) { v[j] = deg[t * 8 + j]; sum += v[j]; }
    sm[t] = sum;
    __syncthreads();
    for (int off = 1; off < 1024; off <<= 1) {
        int x = (t >= off) ? sm[t - off] : 0;
        __syncthreads();
        sm[t] += x;
        __syncthreads();
    }
    int base = sm[t] - sum;
#pragma unroll
    for (int j = 0; j < 8; ++j) {
        rowptr[t * 8 + j] = base;
        cursor[t * 8 + j] = base;
        base += v[j];
    }
    if (t == 1023) rowptr[8192] = base;
}

// ===== fill CSR with pre-normalized alpha + src (kills random reads in aggregate) =====
__global__ void k_fill(const int* __restrict__ adj, const float* __restrict__ elbuf,
                       const float* __restrict__ nodesum, int* __restrict__ cursor,
                       int* __restrict__ src_csr, float* __restrict__ alpha_csr) {
    int e = blockIdx.x * blockDim.x + threadIdx.x;
    if (e >= ETOT) return;
    int s, d; edge_sd(e, adj, s, d);
    int pos = atomicAdd(&cursor[d], 1);
    float4 p = *(const float4*)&elbuf[(size_t)e * 4];
    float4 ns = *(const float4*)&nodesum[d * 4];
    float4 a;
    a.x = p.x * frcp(ns.x); a.y = p.y * frcp(ns.y);
    a.z = p.z * frcp(ns.z); a.w = p.w * frcp(ns.w);
    src_csr[pos] = s;
    *(float4*)&alpha_csr[(size_t)pos * 4] = a;
}

// ===== per-node gather-aggregate: sequential CSR reads + coalesced xw rows =====
__global__ __launch_bounds__(256) void k_aggregate(const int* __restrict__ rowptr,
                                                   const int* __restrict__ src_csr,
                                                   const float* __restrict__ alpha_csr,
                                                   const float* __restrict__ xw,
                                                   const float* __restrict__ bias,
                                                   float* __restrict__ hcat) {
    int n = blockIdx.x * 2 + (threadIdx.x >> 7);
    int c = threadIdx.x & 127;
    int h = c >> 5;
    int beg = rowptr[n], end = rowptr[n + 1];
    float acc = bias[c];
    int i = beg;
    for (; i + 2 <= end; i += 2) {
        int s0 = src_csr[i], s1 = src_csr[i + 1];
        float a0 = alpha_csr[(size_t)i * 4 + h];
        float a1 = alpha_csr[(size_t)(i + 1) * 4 + h];
        acc += a0 * xw[(size_t)s0 * DD + c] + a1 * xw[(size_t)s1 * DD + c];
    }
    if (i < end) {
        int s0 = src_csr[i];
        acc += alpha_csr[(size_t)i * 4 + h] * xw[(size_t)s0 * DD + c];
    }
    hcat[(size_t)n * DD + c] = acc;
}

// ===== q,k projections (32 nodes / block) -> bf16, Q pre-scaled =====
__global__ __launch_bounds__(256) void k_qk(const float* __restrict__ hb,
                                            const float* __restrict__ Wq,
                                            const float* __restrict__ Wk,
                                            unsigned short* __restrict__ Qb,
                                            unsigned short* __restrict__ Kb) {
    const int tid = threadIdx.x;
    const int n0 = blockIdx.x * 32;
    const int t = tid & 127, head = t >> 5, c = t & 31;
    const float* wp = ((tid < 128) ? Wq : Wk) + (size_t)head * DD * NC + c;
    float acc[32];
#pragma unroll
    for (int n = 0; n < 32; ++n) acc[n] = 0.f;
    for (int d = 0; d < DD; d += 4) {
        float w0 = wp[(size_t)d * NC];
        float w1 = wp[(size_t)(d + 1) * NC];
        float w2 = wp[(size_t)(d + 2) * NC];
        float w3 = wp[(size_t)(d + 3) * NC];
#pragma unroll
        for (int n = 0; n < 32; ++n) {
            float4 hv = *(const float4*)&hb[(size_t)(n0 + n) * DD + d];
            acc[n] += hv.x * w0 + hv.y * w1 + hv.z * w2 + hv.w * w3;
        }
    }
    float scale = (tid < 128) ? QK_SCALE : 1.f;
    unsigned short* dst = (tid < 128) ? Qb : Kb;
    dst += ((size_t)head * N_NODES + n0) * NC + c;
#pragma unroll
    for (int n = 0; n < 32; ++n) dst[n * NC] = f2bf(acc[n] * scale);
}

// ===== attention pass A: l_h[n] = sum_m exp2(S) — 64q/block, ksplit 8 =====
__global__ __launch_bounds__(256) void k_attn_l(const unsigned short* __restrict__ Qb,
                                                const unsigned short* __restrict__ Kb,
                                                float* __restrict__ lsum) {
    const int tid = threadIdx.x;
    const int w = tid >> 6;
    const int lane = tid & 63;
    const int lq = lane & 15;
    const int g = lane >> 4;
    const int q0 = blockIdx.x * 64;
    const int ks = blockIdx.y;
    f32x4 zero = {0.f, 0.f, 0.f, 0.f};

    bf16x8 qf[4];
#pragma unroll
    for (int j = 0; j < 4; ++j)
        qf[j] = *(const bf16x8*)(Qb + ((size_t)w * N_NODES + q0 + j * 16 + lq) * NC + g * 8);
    const unsigned short* Kp = Kb + (size_t)w * N_NODES * NC;

    float l[4] = {0.f, 0.f, 0.f, 0.f};
    for (int kt = 0; kt < 16; ++kt) {
        const int k0 = ks * 1024 + kt * 64;
#pragma unroll
        for (int t = 0; t < 4; ++t) {
            const bf16x8 kf = *(const bf16x8*)(Kp + (size_t)(k0 + t * 16 + lq) * NC + g * 8);
#pragma unroll
            for (int j = 0; j < 4; ++j) {
                f32x4 st = __builtin_amdgcn_mfma_f32_16x16x32_bf16(kf, qf[j], zero, 0, 0, 0);
                l[j] += (fexp2(st[0]) + fexp2(st[1])) + (fexp2(st[2]) + fexp2(st[3]));
            }
        }
    }
#pragma unroll
    for (int j = 0; j < 4; ++j) {
        float lj = l[j];
        lj += __shfl_xor(lj, 16); lj += __shfl_xor(lj, 32);
        if (lane < 16) atomicAdd(&lsum[w * N_NODES + q0 + j * 16 + lq], lj);
    }
}

// ===== attention pass B: head-merged PV.  P_sum[q][k] = sum_h exp2(S_h - log2 l_h) =====
__global__ __launch_bounds__(256, 4) void k_attn_pv(
        const unsigned short* __restrict__ Qb,
        const unsigned short* __restrict__ Kb,
        const unsigned short* __restrict__ Htb,
        const float* __restrict__ lsum,
        float* __restrict__ Opart) {
    __shared__ unsigned short htl[128 * 64];    // Ht tile, chunk-rotated (16 KB)
    __shared__ unsigned short plds[32][72];     // head-merged P (32q x 64k), padded rows
    const int tid = threadIdx.x;
    const int w = tid >> 6;
    const int lane = tid & 63;
    const int lq = lane & 15;
    const int g = lane >> 4;
    const int q0 = blockIdx.x * 32;
    const int ks = blockIdx.y;
    const int sd = tid >> 3, sc = tid & 7;
    f32x4 zero = {0.f, 0.f, 0.f, 0.f};

    float lg0[4], lg1[4];
#pragma unroll
    for (int h = 0; h < 4; ++h) {
        lg0[h] = -flog2(lsum[h * N_NODES + q0 + lq]);
        lg1[h] = -flog2(lsum[h * N_NODES + q0 + 16 + lq]);
    }

    f32x4 acc[2][2];   // [d-local][qsub]
#pragma unroll
    for (int a = 0; a < 2; ++a) { acc[a][0] = zero; acc[a][1] = zero; }

    for (int kt = 0; kt < 32; ++kt) {
        const int k0 = ks * 2048 + kt * 64;
        __syncthreads();   // htl/plds consumed by previous PV
#pragma unroll
        for (int mm = 0; mm < 4; ++mm) {
            int d = mm * 32 + sd;
            uint4 v = *(const uint4*)(Htb + (size_t)d * N_NODES + k0 + sc * 8);
            *(uint4*)&htl[d * 64 + ((sc + d) & 7) * 8] = v;
        }
        f32x4 ps0 = zero, ps1 = zero;
#pragma unroll
        for (int h = 0; h < 4; ++h) {
            const bf16x8 kf = *(const bf16x8*)(Kb + ((size_t)h * N_NODES + k0 + w * 16 + lq) * NC + g * 8);
            const bf16x8 qa = *(const bf16x8*)(Qb + ((size_t)h * N_NODES + q0 + lq) * NC + g * 8);
            const bf16x8 qb = *(const bf16x8*)(Qb + ((size_t)h * N_NODES + q0 + 16 + lq) * NC + g * 8);
            f32x4 st0 = __builtin_amdgcn_mfma_f32_16x16x32_bf16(kf, qa, zero, 0, 0, 0);
            f32x4 st1 = __builtin_amdgcn_mfma_f32_16x16x32_bf16(kf, qb, zero, 0, 0, 0);
#pragma unroll
            for (int r = 0; r < 4; ++r) {
                ps0[r] += fexp2(st0[r] + lg0[h]);
                ps1[r] += fexp2(st1[r] + lg1[h]);
            }
        }
        uint2 pk;
        pk.x = pk2bf(ps0[0], ps0[1]); pk.y = pk2bf(ps0[2], ps0[3]);
        *(uint2*)&plds[lq][w * 16 + g * 4] = pk;
        pk.x = pk2bf(ps1[0], ps1[1]); pk.y = pk2bf(ps1[2], ps1[3]);
        *(uint2*)&plds[16 + lq][w * 16 + g * 4] = pk;
        __syncthreads();   // htl + plds staged
#pragma unroll
        for (int kc = 0; kc < 2; ++kc) {
            const bf16x8 af0 = *(const bf16x8*)&plds[lq][kc * 32 + g * 8];
            const bf16x8 af1 = *(const bf16x8*)&plds[16 + lq][kc * 32 + g * 8];
#pragma unroll
            for (int dl = 0; dl < 2; ++dl) {
                int dd = (w * 2 + dl) * 16 + lq;
                const bf16x8 bf = *(const bf16x8*)&htl[dd * 64 + ((kc * 4 + g + dd) & 7) * 8];
                acc[dl][0] = __builtin_amdgcn_mfma_f32_16x16x32_bf16(af0, bf, acc[dl][0], 0, 0, 0);
                acc[dl][1] = __builtin_amdgcn_mfma_f32_16x16x32_bf16(af1, bf, acc[dl][1], 0, 0, 0);
            }
        }
    }
    const size_t ob = (size_t)ks * N_NODES + q0;
#pragma unroll
    for (int dl = 0; dl < 2; ++dl) {
        int d = (w * 2 + dl) * 16 + lq;
#pragma unroll
        for (int s = 0; s < 2; ++s)
#pragma unroll
            for (int r = 0; r < 4; ++r)
                Opart[(ob + s * 16 + 4 * g + r) * DD + d] = acc[dl][s][r];
    }
}

// ===== combine splits, residual, LayerNorm =====
__global__ __launch_bounds__(128) void k_finalize(const float* __restrict__ Opart,
                                                  const float* __restrict__ hb,
                                                  const float* __restrict__ g,
                                                  const float* __restrict__ b,
                                                  float* __restrict__ out) {
    __shared__ float red[2];
    int n = blockIdx.x, c = threadIdx.x;
    const size_t ND = (size_t)N_NODES * DD;
    size_t idx = (size_t)n * DD + c;
    float y = Opart[idx] + Opart[ND + idx] + Opart[2 * ND + idx] + Opart[3 * ND + idx]
            + hb[idx];
    float s = y;
#pragma unroll
    for (int off = 1; off < 64; off <<= 1) s += __shfl_xor(s, off);
    if ((c & 63) == 0) red[c >> 6] = s;
    __syncthreads();
    float mu = (red[0] + red[1]) * (1.f / 128.f);
    float dv = y - mu;
    float vs = dv * dv;
#pragma unroll
    for (int off = 1; off < 64; off <<= 1) vs += __shfl_xor(vs, off);
    __syncthreads();
    if ((c & 63) == 0) red[c >> 6] = vs;
    __syncthreads();
    float rstd = rsqrtf((red[0] + red[1]) * (1.f / 128.f) + LN_EPS);
    out[idx] = dv * rstd * g[c] + b[c];
}

extern "C" void kernel_launch(void* const* d_in, const int* in_sizes, int n_in,
                              void* d_out, int out_size, void* d_ws, size_t ws_size,
                              hipStream_t stream) {
    const float* x        = (const float*)d_in[0];
    const int*   adj      = (const int*)d_in[1];
    const float* Wgat     = (const float*)d_in[2];
    const float* att_src  = (const float*)d_in[3];
    const float* att_dst  = (const float*)d_in[4];
    const float* bias_gat = (const float*)d_in[5];
    const float* Wq       = (const float*)d_in[6];
    const float* Wk       = (const float*)d_in[7];
    const float* Wpro     = (const float*)d_in[8];
    const float* ln_g     = (const float*)d_in[9];
    const float* ln_b     = (const float*)d_in[10];
    float* out = (float*)d_out;

    const size_t ND = (size_t)N_NODES * DD;
    unsigned short* Qb  = (unsigned short*)d_ws;          // 2 MB
    unsigned short* Kb  = Qb + (1 << 20);                 // 2 MB
    unsigned short* Htb = Kb + (1 << 20);                 // 2 MB
    float* xw      = (float*)(Htb + (1 << 20));           // 4 MB
    float* hcat    = xw + ND;                             // 4 MB
    float* hbuf    = hcat + ND;                           // 4 MB
    float* asrc    = hbuf + ND;                           // 128 KB each below
    float* adst    = asrc + N_NODES * NH;
    float* nodesum = adst + N_NODES * NH;                 // [N*4] (memset w/ lsum)
    float* lsum    = nodesum + N_NODES * NH;              // [N*4]
    float* elbuf   = lsum + N_NODES * NH;                 // ETOT*4 floats (4.3 MB)
    int*   deg     = (int*)(elbuf + (size_t)ETOT * 4);
    int*   rowptr  = deg + 8192;
    int*   cursor  = rowptr + 8704;
    int*   src_csr = cursor + 8704;                       // ETOT ints
    float* alpha_csr = (float*)(src_csr + ETOT);          // ETOT*4 floats (4.3 MB)
    float* Opart   = alpha_csr + (size_t)ETOT * 4;        // 4 splits x [N,128] = 16 MB

    hipMemsetAsync(nodesum, 0, 2 * N_NODES * NH * sizeof(float), stream);  // nodesum+lsum
    hipMemsetAsync(deg, 0, N_NODES * sizeof(int), stream);
    k_gemm_att<<<N_NODES / 16, 128, 0, stream>>>(x, Wgat, xw, att_src, att_dst, asrc, adst);
    int eblocks = (ETOT + 255) / 256;
    k_edge_pass1<<<eblocks, 256, 0, stream>>>(adj, asrc, adst, elbuf, nodesum, deg);
    k_scan<<<1, 1024, 0, stream>>>(deg, rowptr, cursor);
    k_fill<<<eblocks, 256, 0, stream>>>(adj, elbuf, nodesum, cursor, src_csr, alpha_csr);
    k_aggregate<<<N_NODES / 2, 256, 0, stream>>>(rowptr, src_csr, alpha_csr, xw, bias_gat, hcat);
    k_gemm_pro<<<N_NODES / 16, 128, 0, stream>>>(hcat, Wpro, hbuf, Htb);
    k_qk<<<N_NODES / 32, 256, 0, stream>>>(hbuf, Wq, Wk, Qb, Kb);
    dim3 lgrid(N_NODES / 64, 8);
    k_attn_l<<<lgrid, 256, 0, stream>>>(Qb, Kb, lsum);
    dim3 agrid(N_NODES / 32, 4);
    k_attn_pv<<<agrid, 256, 0, stream>>>(Qb, Kb, Htb, lsum, Opart);
    k_finalize<<<N_NODES, 128, 0, stream>>>(Opart, hbuf, ln_g, ln_b, out);
}

// Round 7
// 374.170 us; speedup vs baseline: 1.1488x; 1.1488x over previous
//
#include <hip/hip_runtime.h>
#include <math.h>

#define N_NODES 8192
#define E_EDGES 262144
#define ETOT (E_EDGES + N_NODES)
#define F_IN 256
#define NH 4
#define NC 32
#define DD 128
#define NEG_SLOPE 0.2f
#define LN_EPS 1e-5f
// attention softmax in exp2 domain: fold log2(e)/sqrt(32) into Q at pack time
#define QK_SCALE (1.4426950408889634f / 5.656854249492381f)

typedef __attribute__((ext_vector_type(8))) short bf16x8;
typedef __attribute__((ext_vector_type(4))) float f32x4;

__device__ __forceinline__ float fexp2(float x) { return __builtin_amdgcn_exp2f(x); }
__device__ __forceinline__ float flog2(float x) { return __builtin_amdgcn_logf(x); }
__device__ __forceinline__ float frcp(float x)  { return __builtin_amdgcn_rcpf(x); }

__device__ __forceinline__ unsigned short f2bf(float f) {   // RTNE
    unsigned u = __float_as_uint(f);
    u += 0x7FFFu + ((u >> 16) & 1u);
    return (unsigned short)(u >> 16);
}
// pack two floats -> two bf16 (round-half-up) in one v_perm
__device__ __forceinline__ unsigned pk2bf(float lo, float hi) {
    unsigned a = __float_as_uint(lo) + 0x8000u;
    unsigned b = __float_as_uint(hi) + 0x8000u;
    return __builtin_amdgcn_perm(b, a, 0x07060302u);
}

// ===== GEMM xw = x @ Wgat (K=256), LDS-staged A, fused attcoef epilogue =====
__global__ __launch_bounds__(128) void k_gemm_att(const float* __restrict__ A,
                                                  const float* __restrict__ W,
                                                  float* __restrict__ out,
                                                  const float* __restrict__ att_src,
                                                  const float* __restrict__ att_dst,
                                                  float* __restrict__ asrc,
                                                  float* __restrict__ adst) {
    __shared__ float as[16][F_IN];
    const int tid = threadIdx.x;
    const int r0 = blockIdx.x * 16;
    for (int idx = tid; idx < 16 * F_IN; idx += 128)
        as[idx >> 8][idx & 255] = A[(size_t)r0 * F_IN + idx];
    __syncthreads();
    float acc[16];
#pragma unroll
    for (int r = 0; r < 16; ++r) acc[r] = 0.f;
    for (int k = 0; k < F_IN; k += 4) {
        float w0 = W[(size_t)k * 128 + tid];
        float w1 = W[(size_t)(k + 1) * 128 + tid];
        float w2 = W[(size_t)(k + 2) * 128 + tid];
        float w3 = W[(size_t)(k + 3) * 128 + tid];
#pragma unroll
        for (int r = 0; r < 16; ++r) {
            float4 av = *(const float4*)&as[r][k];
            acc[r] += av.x * w0 + av.y * w1 + av.z * w2 + av.w * w3;
        }
    }
#pragma unroll
    for (int r = 0; r < 16; ++r) out[(size_t)(r0 + r) * 128 + tid] = acc[r];
    float avs = att_src[tid], avd = att_dst[tid];
    int h = tid >> 5;
#pragma unroll
    for (int r = 0; r < 16; ++r) {
        float vs = acc[r] * avs, vd = acc[r] * avd;
#pragma unroll
        for (int off = 1; off < 32; off <<= 1) {
            vs += __shfl_xor(vs, off);
            vd += __shfl_xor(vd, off);
        }
        if ((tid & 31) == 0) {
            asrc[(r0 + r) * 4 + h] = vs;
            adst[(r0 + r) * 4 + h] = vd;
        }
    }
}

// ===== GEMM hbuf = hcat @ Wpro + Htb transpose + FUSED q/k projections =====
__global__ __launch_bounds__(128) void k_gemm_pro(const float* __restrict__ A,
                                                  const float* __restrict__ W,
                                                  const float* __restrict__ Wq,
                                                  const float* __restrict__ Wk,
                                                  float* __restrict__ out,
                                                  unsigned short* __restrict__ Htb,
                                                  unsigned short* __restrict__ Qb,
                                                  unsigned short* __restrict__ Kb) {
    __shared__ float as[16][DD];
    __shared__ float hs[16][DD];
    const int tid = threadIdx.x;
    const int r0 = blockIdx.x * 16;
    for (int idx = tid; idx < 16 * DD; idx += 128)
        as[idx >> 7][idx & 127] = A[(size_t)r0 * DD + idx];
    __syncthreads();
    float acc[16];
#pragma unroll
    for (int r = 0; r < 16; ++r) acc[r] = 0.f;
    for (int k = 0; k < DD; k += 4) {
        float w0 = W[(size_t)k * 128 + tid];
        float w1 = W[(size_t)(k + 1) * 128 + tid];
        float w2 = W[(size_t)(k + 2) * 128 + tid];
        float w3 = W[(size_t)(k + 3) * 128 + tid];
#pragma unroll
        for (int r = 0; r < 16; ++r) {
            float4 av = *(const float4*)&as[r][k];
            acc[r] += av.x * w0 + av.y * w1 + av.z * w2 + av.w * w3;
        }
    }
#pragma unroll
    for (int r = 0; r < 16; ++r) {
        out[(size_t)(r0 + r) * 128 + tid] = acc[r];
        hs[r][tid] = acc[r];
    }
    uint4 p0, p1;
    p0.x = (unsigned)f2bf(acc[0]) | ((unsigned)f2bf(acc[1]) << 16);
    p0.y = (unsigned)f2bf(acc[2]) | ((unsigned)f2bf(acc[3]) << 16);
    p0.z = (unsigned)f2bf(acc[4]) | ((unsigned)f2bf(acc[5]) << 16);
    p0.w = (unsigned)f2bf(acc[6]) | ((unsigned)f2bf(acc[7]) << 16);
    p1.x = (unsigned)f2bf(acc[8]) | ((unsigned)f2bf(acc[9]) << 16);
    p1.y = (unsigned)f2bf(acc[10]) | ((unsigned)f2bf(acc[11]) << 16);
    p1.z = (unsigned)f2bf(acc[12]) | ((unsigned)f2bf(acc[13]) << 16);
    p1.w = (unsigned)f2bf(acc[14]) | ((unsigned)f2bf(acc[15]) << 16);
    *(uint4*)(Htb + (size_t)tid * N_NODES + r0) = p0;
    *(uint4*)(Htb + (size_t)tid * N_NODES + r0 + 8) = p1;
    __syncthreads();
    // q/k projections for these 16 nodes: thread = (head, c)
    const int head = tid >> 5, c = tid & 31;
    const float* wq = Wq + (size_t)head * DD * NC + c;
    const float* wk = Wk + (size_t)head * DD * NC + c;
    float q[16], kk[16];
#pragma unroll
    for (int n = 0; n < 16; ++n) { q[n] = 0.f; kk[n] = 0.f; }
    for (int d = 0; d < DD; d += 4) {
        float wq0 = wq[(size_t)d * NC],       wk0 = wk[(size_t)d * NC];
        float wq1 = wq[(size_t)(d + 1) * NC], wk1 = wk[(size_t)(d + 1) * NC];
        float wq2 = wq[(size_t)(d + 2) * NC], wk2 = wk[(size_t)(d + 2) * NC];
        float wq3 = wq[(size_t)(d + 3) * NC], wk3 = wk[(size_t)(d + 3) * NC];
#pragma unroll
        for (int n = 0; n < 16; ++n) {
            float4 hv = *(const float4*)&hs[n][d];   // broadcast, conflict-free
            q[n]  += hv.x * wq0 + hv.y * wq1 + hv.z * wq2 + hv.w * wq3;
            kk[n] += hv.x * wk0 + hv.y * wk1 + hv.z * wk2 + hv.w * wk3;
        }
    }
    unsigned short* qdst = Qb + ((size_t)head * N_NODES + r0) * NC + c;
    unsigned short* kdst = Kb + ((size_t)head * N_NODES + r0) * NC + c;
#pragma unroll
    for (int n = 0; n < 16; ++n) {
        qdst[n * NC] = f2bf(q[n] * QK_SCALE);
        kdst[n * NC] = f2bf(kk[n]);
    }
}

__device__ __forceinline__ void edge_sd(int e, const int* adj, int& s, int& d) {
    if (e < E_EDGES) { s = adj[e]; d = adj[E_EDGES + e]; }
    else { s = e - E_EDGES; d = s; }
}

// ===== edge pass: degree count + exp(leaky) + denom sum =====
__global__ void k_edge_pass1(const int* __restrict__ adj, const float* __restrict__ asrc,
                             const float* __restrict__ adst, float* __restrict__ elbuf,
                             float* __restrict__ nodesum, int* __restrict__ deg) {
    int e = blockIdx.x * blockDim.x + threadIdx.x;
    if (e >= ETOT) return;
    int s, d; edge_sd(e, adj, s, d);
    atomicAdd(&deg[d], 1);
    float4 as4 = *(const float4*)&asrc[s * 4];
    float4 ad4 = *(const float4*)&adst[d * 4];
    const float L2E = 1.4426950408889634f;
    float4 p;
    float v;
    v = as4.x + ad4.x; v = v > 0.f ? v : NEG_SLOPE * v; p.x = fexp2(v * L2E);
    v = as4.y + ad4.y; v = v > 0.f ? v : NEG_SLOPE * v; p.y = fexp2(v * L2E);
    v = as4.z + ad4.z; v = v > 0.f ? v : NEG_SLOPE * v; p.z = fexp2(v * L2E);
    v = as4.w + ad4.w; v = v > 0.f ? v : NEG_SLOPE * v; p.w = fexp2(v * L2E);
    *(float4*)&elbuf[(size_t)e * 4] = p;
    atomicAdd(&nodesum[d * 4 + 0], p.x);
    atomicAdd(&nodesum[d * 4 + 1], p.y);
    atomicAdd(&nodesum[d * 4 + 2], p.z);
    atomicAdd(&nodesum[d * 4 + 3], p.w);
}

// ===== single-block exclusive scan over deg[8192] -> rowptr, cursor =====
__global__ __launch_bounds__(1024) void k_scan(const int* __restrict__ deg,
                                               int* __restrict__ rowptr,
                                               int* __restrict__ cursor) {
    __shared__ int sm[1024];
    int t = threadIdx.x;
    int v[8], sum = 0;
#pragma unroll
    for (int j = 0; j < 8; ++j) { v[j] = deg[t * 8 + j]; sum += v[j]; }
    sm[t] = sum;
    __syncthreads();
    for (int off = 1; off < 1024; off <<= 1) {
        int x = (t >= off) ? sm[t - off] : 0;
        __syncthreads();
        sm[t] += x;
        __syncthreads();
    }
    int base = sm[t] - sum;
#pragma unroll
    for (int j = 0; j < 8; ++j) {
        rowptr[t * 8 + j] = base;
        cursor[t * 8 + j] = base;
        base += v[j];
    }
    if (t == 1023) rowptr[8192] = base;
}

// ===== fill CSR with pre-normalized alpha + src =====
__global__ void k_fill(const int* __restrict__ adj, const float* __restrict__ elbuf,
                       const float* __restrict__ nodesum, int* __restrict__ cursor,
                       int* __restrict__ src_csr, float* __restrict__ alpha_csr) {
    int e = blockIdx.x * blockDim.x + threadIdx.x;
    if (e >= ETOT) return;
    int s, d; edge_sd(e, adj, s, d);
    int pos = atomicAdd(&cursor[d], 1);
    float4 p = *(const float4*)&elbuf[(size_t)e * 4];
    float4 ns = *(const float4*)&nodesum[d * 4];
    float4 a;
    a.x = p.x * frcp(ns.x); a.y = p.y * frcp(ns.y);
    a.z = p.z * frcp(ns.z); a.w = p.w * frcp(ns.w);
    src_csr[pos] = s;
    *(float4*)&alpha_csr[(size_t)pos * 4] = a;
}

// ===== per-node gather-aggregate: sequential CSR reads + coalesced xw rows =====
__global__ __launch_bounds__(256) void k_aggregate(const int* __restrict__ rowptr,
                                                   const int* __restrict__ src_csr,
                                                   const float* __restrict__ alpha_csr,
                                                   const float* __restrict__ xw,
                                                   const float* __restrict__ bias,
                                                   float* __restrict__ hcat) {
    int n = blockIdx.x * 2 + (threadIdx.x >> 7);
    int c = threadIdx.x & 127;
    int h = c >> 5;
    int beg = rowptr[n], end = rowptr[n + 1];
    float acc = bias[c];
    int i = beg;
    for (; i + 2 <= end; i += 2) {
        int s0 = src_csr[i], s1 = src_csr[i + 1];
        float a0 = alpha_csr[(size_t)i * 4 + h];
        float a1 = alpha_csr[(size_t)(i + 1) * 4 + h];
        acc += a0 * xw[(size_t)s0 * DD + c] + a1 * xw[(size_t)s1 * DD + c];
    }
    if (i < end) {
        int s0 = src_csr[i];
        acc += alpha_csr[(size_t)i * 4 + h] * xw[(size_t)s0 * DD + c];
    }
    hcat[(size_t)n * DD + c] = acc;
}

// ===== attention pass A: l_h[n] = sum_m exp2(S) — 64q/block, ksplit 8 =====
__global__ __launch_bounds__(256) void k_attn_l(const unsigned short* __restrict__ Qb,
                                                const unsigned short* __restrict__ Kb,
                                                float* __restrict__ lsum) {
    const int tid = threadIdx.x;
    const int w = tid >> 6;
    const int lane = tid & 63;
    const int lq = lane & 15;
    const int g = lane >> 4;
    const int q0 = blockIdx.x * 64;
    const int ks = blockIdx.y;
    f32x4 zero = {0.f, 0.f, 0.f, 0.f};

    bf16x8 qf[4];
#pragma unroll
    for (int j = 0; j < 4; ++j)
        qf[j] = *(const bf16x8*)(Qb + ((size_t)w * N_NODES + q0 + j * 16 + lq) * NC + g * 8);
    const unsigned short* Kp = Kb + (size_t)w * N_NODES * NC;

    float l[4] = {0.f, 0.f, 0.f, 0.f};
    for (int kt = 0; kt < 16; ++kt) {
        const int k0 = ks * 1024 + kt * 64;
#pragma unroll
        for (int t = 0; t < 4; ++t) {
            const bf16x8 kf = *(const bf16x8*)(Kp + (size_t)(k0 + t * 16 + lq) * NC + g * 8);
#pragma unroll
            for (int j = 0; j < 4; ++j) {
                f32x4 st = __builtin_amdgcn_mfma_f32_16x16x32_bf16(kf, qf[j], zero, 0, 0, 0);
                l[j] += (fexp2(st[0]) + fexp2(st[1])) + (fexp2(st[2]) + fexp2(st[3]));
            }
        }
    }
#pragma unroll
    for (int j = 0; j < 4; ++j) {
        float lj = l[j];
        lj += __shfl_xor(lj, 16); lj += __shfl_xor(lj, 32);
        if (lane < 16) atomicAdd(&lsum[w * N_NODES + q0 + j * 16 + lq], lj);
    }
}

// ===== attention pass B: head-merged PV, Q-frags hoisted to registers =====
__global__ __launch_bounds__(256, 2) void k_attn_pv(
        const unsigned short* __restrict__ Qb,
        const unsigned short* __restrict__ Kb,
        const unsigned short* __restrict__ Htb,
        const float* __restrict__ lsum,
        float* __restrict__ Opart) {
    __shared__ unsigned short htl[128 * 64];    // Ht tile, chunk-rotated (16 KB)
    __shared__ unsigned short plds[32][72];     // head-merged P (32q x 64k), padded rows
    const int tid = threadIdx.x;
    const int w = tid >> 6;
    const int lane = tid & 63;
    const int lq = lane & 15;
    const int g = lane >> 4;
    const int q0 = blockIdx.x * 32;
    const int ks = blockIdx.y;
    const int sd = tid >> 3, sc = tid & 7;
    f32x4 zero = {0.f, 0.f, 0.f, 0.f};

    // hoist: -log2(l) and Q fragments (loop-invariant) into registers
    float lg0[4], lg1[4];
    bf16x8 qreg0[4], qreg1[4];
#pragma unroll
    for (int h = 0; h < 4; ++h) {
        lg0[h] = -flog2(lsum[h * N_NODES + q0 + lq]);
        lg1[h] = -flog2(lsum[h * N_NODES + q0 + 16 + lq]);
        qreg0[h] = *(const bf16x8*)(Qb + ((size_t)h * N_NODES + q0 + lq) * NC + g * 8);
        qreg1[h] = *(const bf16x8*)(Qb + ((size_t)h * N_NODES + q0 + 16 + lq) * NC + g * 8);
    }

    f32x4 acc[2][2];   // [d-local][qsub]
#pragma unroll
    for (int a = 0; a < 2; ++a) { acc[a][0] = zero; acc[a][1] = zero; }

    for (int kt = 0; kt < 32; ++kt) {
        const int k0 = ks * 2048 + kt * 64;
        __syncthreads();   // htl/plds consumed by previous PV
#pragma unroll
        for (int mm = 0; mm < 4; ++mm) {
            int d = mm * 32 + sd;
            uint4 v = *(const uint4*)(Htb + (size_t)d * N_NODES + k0 + sc * 8);
            *(uint4*)&htl[d * 64 + ((sc + d) & 7) * 8] = v;
        }
        f32x4 ps0 = zero, ps1 = zero;
#pragma unroll
        for (int h = 0; h < 4; ++h) {
            const bf16x8 kf = *(const bf16x8*)(Kb + ((size_t)h * N_NODES + k0 + w * 16 + lq) * NC + g * 8);
            f32x4 st0 = __builtin_amdgcn_mfma_f32_16x16x32_bf16(kf, qreg0[h], zero, 0, 0, 0);
            f32x4 st1 = __builtin_amdgcn_mfma_f32_16x16x32_bf16(kf, qreg1[h], zero, 0, 0, 0);
#pragma unroll
            for (int r = 0; r < 4; ++r) {
                ps0[r] += fexp2(st0[r] + lg0[h]);
                ps1[r] += fexp2(st1[r] + lg1[h]);
            }
        }
        uint2 pk;
        pk.x = pk2bf(ps0[0], ps0[1]); pk.y = pk2bf(ps0[2], ps0[3]);
        *(uint2*)&plds[lq][w * 16 + g * 4] = pk;
        pk.x = pk2bf(ps1[0], ps1[1]); pk.y = pk2bf(ps1[2], ps1[3]);
        *(uint2*)&plds[16 + lq][w * 16 + g * 4] = pk;
        __syncthreads();   // htl + plds staged
#pragma unroll
        for (int kc = 0; kc < 2; ++kc) {
            const bf16x8 af0 = *(const bf16x8*)&plds[lq][kc * 32 + g * 8];
            const bf16x8 af1 = *(const bf16x8*)&plds[16 + lq][kc * 32 + g * 8];
#pragma unroll
            for (int dl = 0; dl < 2; ++dl) {
                int dd = (w * 2 + dl) * 16 + lq;
                const bf16x8 bf = *(const bf16x8*)&htl[dd * 64 + ((kc * 4 + g + dd) & 7) * 8];
                acc[dl][0] = __builtin_amdgcn_mfma_f32_16x16x32_bf16(af0, bf, acc[dl][0], 0, 0, 0);
                acc[dl][1] = __builtin_amdgcn_mfma_f32_16x16x32_bf16(af1, bf, acc[dl][1], 0, 0, 0);
            }
        }
    }
    const size_t ob = (size_t)ks * N_NODES + q0;
#pragma unroll
    for (int dl = 0; dl < 2; ++dl) {
        int d = (w * 2 + dl) * 16 + lq;
#pragma unroll
        for (int s = 0; s < 2; ++s)
#pragma unroll
            for (int r = 0; r < 4; ++r)
                Opart[(ob + s * 16 + 4 * g + r) * DD + d] = acc[dl][s][r];
    }
}

// ===== combine splits, residual, LayerNorm =====
__global__ __launch_bounds__(128) void k_finalize(const float* __restrict__ Opart,
                                                  const float* __restrict__ hb,
                                                  const float* __restrict__ g,
                                                  const float* __restrict__ b,
                                                  float* __restrict__ out) {
    __shared__ float red[2];
    int n = blockIdx.x, c = threadIdx.x;
    const size_t ND = (size_t)N_NODES * DD;
    size_t idx = (size_t)n * DD + c;
    float y = Opart[idx] + Opart[ND + idx] + Opart[2 * ND + idx] + Opart[3 * ND + idx]
            + hb[idx];
    float s = y;
#pragma unroll
    for (int off = 1; off < 64; off <<= 1) s += __shfl_xor(s, off);
    if ((c & 63) == 0) red[c >> 6] = s;
    __syncthreads();
    float mu = (red[0] + red[1]) * (1.f / 128.f);
    float dv = y - mu;
    float vs = dv * dv;
#pragma unroll
    for (int off = 1; off < 64; off <<= 1) vs += __shfl_xor(vs, off);
    __syncthreads();
    if ((c & 63) == 0) red[c >> 6] = vs;
    __syncthreads();
    float rstd = rsqrtf((red[0] + red[1]) * (1.f / 128.f) + LN_EPS);
    out[idx] = dv * rstd * g[c] + b[c];
}

extern "C" void kernel_launch(void* const* d_in, const int* in_sizes, int n_in,
                              void* d_out, int out_size, void* d_ws, size_t ws_size,
                              hipStream_t stream) {
    const float* x        = (const float*)d_in[0];
    const int*   adj      = (const int*)d_in[1];
    const float* Wgat     = (const float*)d_in[2];
    const float* att_src  = (const float*)d_in[3];
    const float* att_dst  = (const float*)d_in[4];
    const float* bias_gat = (const float*)d_in[5];
    const float* Wq       = (const float*)d_in[6];
    const float* Wk       = (const float*)d_in[7];
    const float* Wpro     = (const float*)d_in[8];
    const float* ln_g     = (const float*)d_in[9];
    const float* ln_b     = (const float*)d_in[10];
    float* out = (float*)d_out;

    const size_t ND = (size_t)N_NODES * DD;
    unsigned short* Qb  = (unsigned short*)d_ws;          // 2 MB
    unsigned short* Kb  = Qb + (1 << 20);                 // 2 MB
    unsigned short* Htb = Kb + (1 << 20);                 // 2 MB
    float* xw      = (float*)(Htb + (1 << 20));           // 4 MB
    float* hcat    = xw + ND;                             // 4 MB
    float* hbuf    = hcat + ND;                           // 4 MB
    float* asrc    = hbuf + ND;                           // 128 KB each below
    float* adst    = asrc + N_NODES * NH;
    float* nodesum = adst + N_NODES * NH;                 // [N*4] (memset w/ lsum)
    float* lsum    = nodesum + N_NODES * NH;              // [N*4]
    float* elbuf   = lsum + N_NODES * NH;                 // ETOT*4 floats (4.3 MB)
    int*   deg     = (int*)(elbuf + (size_t)ETOT * 4);
    int*   rowptr  = deg + 8192;
    int*   cursor  = rowptr + 8704;
    int*   src_csr = cursor + 8704;                       // ETOT ints
    float* alpha_csr = (float*)(src_csr + ETOT);          // ETOT*4 floats (4.3 MB)
    float* Opart   = alpha_csr + (size_t)ETOT * 4;        // 4 splits x [N,128] = 16 MB

    hipMemsetAsync(nodesum, 0, 2 * N_NODES * NH * sizeof(float), stream);  // nodesum+lsum
    hipMemsetAsync(deg, 0, N_NODES * sizeof(int), stream);
    k_gemm_att<<<N_NODES / 16, 128, 0, stream>>>(x, Wgat, xw, att_src, att_dst, asrc, adst);
    int eblocks = (ETOT + 255) / 256;
    k_edge_pass1<<<eblocks, 256, 0, stream>>>(adj, asrc, adst, elbuf, nodesum, deg);
    k_scan<<<1, 1024, 0, stream>>>(deg, rowptr, cursor);
    k_fill<<<eblocks, 256, 0, stream>>>(adj, elbuf, nodesum, cursor, src_csr, alpha_csr);
    k_aggregate<<<N_NODES / 2, 256, 0, stream>>>(rowptr, src_csr, alpha_csr, xw, bias_gat, hcat);
    k_gemm_pro<<<N_NODES / 16, 128, 0, stream>>>(hcat, Wpro, Wq, Wk, hbuf, Htb, Qb, Kb);
    dim3 lgrid(N_NODES / 64, 8);
    k_attn_l<<<lgrid, 256, 0, stream>>>(Qb, Kb, lsum);
    dim3 agrid(N_NODES / 32, 4);
    k_attn_pv<<<agrid, 256, 0, stream>>>(Qb, Kb, Htb, lsum, Opart);
    k_finalize<<<N_NODES, 128, 0, stream>>>(Opart, hbuf, ln_g, ln_b, out);
}